// Round 1
// baseline (744.530 us; speedup 1.0000x reference)
//
#include <hip/hip_runtime.h>
#include <hip/hip_bf16.h>

#define B_  16
#define S_  4096
#define D_  512
#define M_  2048
#define ROWS (B_ * S_)   // 65536
#define N3D  (3 * D_)    // 1536

typedef __attribute__((ext_vector_type(8))) short bf16x8;
typedef __attribute__((ext_vector_type(4))) float f32x4;

// ---------------- conversions ----------------

__global__ __launch_bounds__(256) void cvt_x_kernel(const float* __restrict__ x,
                                                    __hip_bfloat16* __restrict__ xb) {
    long i = (long)blockIdx.x * 256 + threadIdx.x;   // i in [0, ROWS*D_/8)
    const float4* x4 = (const float4*)x;
    float4 a = x4[2 * i], b = x4[2 * i + 1];
    union { __hip_bfloat16 h[8]; int4 v; } u;
    u.h[0] = __float2bfloat16(a.x); u.h[1] = __float2bfloat16(a.y);
    u.h[2] = __float2bfloat16(a.z); u.h[3] = __float2bfloat16(a.w);
    u.h[4] = __float2bfloat16(b.x); u.h[5] = __float2bfloat16(b.y);
    u.h[6] = __float2bfloat16(b.z); u.h[7] = __float2bfloat16(b.w);
    ((int4*)xb)[i] = u.v;
}

// W_qkv (D x 3D, row-major) -> Wt (3D x D) bf16, transposed
__global__ __launch_bounds__(256) void cvt_w_kernel(const float* __restrict__ w,
                                                    __hip_bfloat16* __restrict__ wt) {
    int idx = blockIdx.x * 256 + threadIdx.x;  // [0, N3D*D_)
    int n = idx >> 9, k = idx & 511;
    wt[idx] = __float2bfloat16(w[(long)k * N3D + n]);
}

// ---------------- qkv GEMM ----------------
// C[65536 x 1536] = Xb[65536 x 512] @ Wt^T + bias; scatter cols to q/k (fp32) and v (bf16)
__global__ __launch_bounds__(256) void gemm_qkv_kernel(
    const __hip_bfloat16* __restrict__ Xb,
    const __hip_bfloat16* __restrict__ Wt,
    const float* __restrict__ bias,
    float* __restrict__ qout, float* __restrict__ kout,
    __hip_bfloat16* __restrict__ vout)
{
    __shared__ __hip_bfloat16 As[128][40];   // +8 bf16 pad: row stride 80B, conflict-free-ish
    __shared__ __hip_bfloat16 Bs[128][40];
    const int tid  = threadIdx.x;
    const int m0   = blockIdx.x * 128;
    const int n0   = blockIdx.y * 128;
    const int wave = tid >> 6, lane = tid & 63;
    const int wm   = (wave >> 1) * 64, wn = (wave & 1) * 64;
    const int quad = lane >> 4, l16 = lane & 15;

    const int srow  = tid >> 2;        // 0..63
    const int skcol = (tid & 3) * 8;   // 0,8,16,24

    f32x4 acc[4][4] = {};

    for (int k0 = 0; k0 < 512; k0 += 32) {
        int4 a0 = *(const int4*)(Xb + (long)(m0 + srow)      * 512 + k0 + skcol);
        int4 a1 = *(const int4*)(Xb + (long)(m0 + srow + 64) * 512 + k0 + skcol);
        int4 b0 = *(const int4*)(Wt + (long)(n0 + srow)      * 512 + k0 + skcol);
        int4 b1 = *(const int4*)(Wt + (long)(n0 + srow + 64) * 512 + k0 + skcol);
        __syncthreads();
        *(int4*)&As[srow][skcol]      = a0;
        *(int4*)&As[srow + 64][skcol] = a1;
        *(int4*)&Bs[srow][skcol]      = b0;
        *(int4*)&Bs[srow + 64][skcol] = b1;
        __syncthreads();

        bf16x8 af[4], bf[4];
        #pragma unroll
        for (int t = 0; t < 4; t++) {
            af[t] = *(const bf16x8*)&As[wm + t * 16 + l16][quad * 8];
            bf[t] = *(const bf16x8*)&Bs[wn + t * 16 + l16][quad * 8];
        }
        #pragma unroll
        for (int mt = 0; mt < 4; mt++)
            #pragma unroll
            for (int nt = 0; nt < 4; nt++)
                acc[mt][nt] = __builtin_amdgcn_mfma_f32_16x16x32_bf16(
                    af[mt], bf[nt], acc[mt][nt], 0, 0, 0);
    }

    #pragma unroll
    for (int mt = 0; mt < 4; mt++) {
        #pragma unroll
        for (int nt = 0; nt < 4; nt++) {
            int col = n0 + wn + nt * 16 + l16;
            float bcol = bias[col];
            #pragma unroll
            for (int r = 0; r < 4; r++) {
                int row = m0 + wm + mt * 16 + quad * 4 + r;
                float val = acc[mt][nt][r] + bcol;
                if (col < 512)        qout[(long)row * 512 + col]          = val;
                else if (col < 1024)  kout[(long)row * 512 + (col - 512)]  = val;
                else                  vout[(long)row * 512 + (col - 1024)] = __float2bfloat16(val);
            }
        }
    }
}

// ---------------- attention ----------------

__global__ __launch_bounds__(256) void scores_kernel(
    const float* __restrict__ q, const float* __restrict__ k, float* __restrict__ sc)
{
    __shared__ float ql[512];
    int b = blockIdx.x, tid = threadIdx.x;
    const float* qrow = q + (long)(b * S_ + S_ - 1) * 512;
    ql[tid]       = qrow[tid];
    ql[tid + 256] = qrow[tid + 256];
    __syncthreads();
    int wave = tid >> 6, lane = tid & 63;
    int s0 = blockIdx.y * 64;
    float4 q1 = *(const float4*)&ql[lane * 8];
    float4 q2 = *(const float4*)&ql[lane * 8 + 4];
    for (int s = s0 + wave; s < s0 + 64; s += 4) {
        const float4* kr = (const float4*)(k + ((long)b * S_ + s) * 512);
        float4 x1 = kr[lane * 2], x2 = kr[lane * 2 + 1];
        float acc = x1.x * q1.x + x1.y * q1.y + x1.z * q1.z + x1.w * q1.w
                  + x2.x * q2.x + x2.y * q2.y + x2.z * q2.z + x2.w * q2.w;
        #pragma unroll
        for (int off = 32; off; off >>= 1) acc += __shfl_xor(acc, off);
        if (lane == 0) sc[(long)b * S_ + s] = acc;
    }
}

__global__ __launch_bounds__(256) void softmax_kernel(const float* __restrict__ sc,
                                                      float* __restrict__ attn)
{
    int b = blockIdx.x, tid = threadIdx.x;
    __shared__ float red[256];
    const float* row = sc + (long)b * S_;
    float mx = -1e30f;
    for (int s = tid; s < S_; s += 256) mx = fmaxf(mx, row[s]);
    red[tid] = mx; __syncthreads();
    for (int o = 128; o; o >>= 1) { if (tid < o) red[tid] = fmaxf(red[tid], red[tid + o]); __syncthreads(); }
    mx = red[0]; __syncthreads();
    float sum = 0.f;
    float* arow = attn + (long)b * S_;
    for (int s = tid; s < S_; s += 256) { float e = __expf(row[s] - mx); arow[s] = e; sum += e; }
    red[tid] = sum; __syncthreads();
    for (int o = 128; o; o >>= 1) { if (tid < o) red[tid] += red[tid + o]; __syncthreads(); }
    float inv = 1.0f / red[0];
    for (int s = tid; s < S_; s += 256) arow[s] *= inv;
}

__global__ __launch_bounds__(256) void h_init_kernel(const float* __restrict__ x,
                                                     float* __restrict__ h) {
    int i = blockIdx.x * 256 + threadIdx.x;  // [0, 16*512)
    int b = i >> 9, d = i & 511;
    h[i] = x[(long)(b * S_ + S_ - 1) * 512 + d];
}

__global__ __launch_bounds__(256) void sa_kernel(const __hip_bfloat16* __restrict__ v,
                                                 const float* __restrict__ attn,
                                                 float* __restrict__ h)
{
    int b  = blockIdx.x;
    int d0 = blockIdx.y * 128;   // 4 chunks
    int s0 = blockIdx.z * 512;   // 8 chunks
    int tid = threadIdx.x;
    int dt = (tid & 63) * 2;
    int sg = tid >> 6;
    float a0 = 0.f, a1 = 0.f;
    for (int s = s0 + sg; s < s0 + 512; s += 4) {
        float w = attn[(long)b * S_ + s];
        __hip_bfloat162 vv = *(const __hip_bfloat162*)(v + ((long)(b * S_ + s)) * 512 + d0 + dt);
        float2 vf = __bfloat1622float2(vv);
        a0 += w * vf.x; a1 += w * vf.y;
    }
    atomicAdd(&h[b * 512 + d0 + dt],     a0);
    atomicAdd(&h[b * 512 + d0 + dt + 1], a1);
}

// ---------------- MLP ----------------

__global__ __launch_bounds__(256) void mlp1_kernel(const float* __restrict__ h,
    const float* __restrict__ W1, const float* __restrict__ b1, float* __restrict__ h1)
{
    int b = blockIdx.x;
    int j = blockIdx.y * 256 + threadIdx.x;
    __shared__ float hs[512];
    hs[threadIdx.x]       = h[b * 512 + threadIdx.x];
    hs[threadIdx.x + 256] = h[b * 512 + threadIdx.x + 256];
    __syncthreads();
    float acc = 0.f;
    for (int k2 = 0; k2 < 512; k2++) acc += hs[k2] * W1[(long)k2 * M_ + j];
    acc += b1[j];
    h1[(long)b * M_ + j] = fmaxf(acc, 0.f);
}

__global__ __launch_bounds__(256) void mlp2_kernel(const float* __restrict__ h1,
    const float* __restrict__ W2, const float* __restrict__ b2, float* __restrict__ h2)
{
    int b = blockIdx.x;
    int j = blockIdx.y * 256 + threadIdx.x;
    __shared__ float hs[2048];
    for (int t = threadIdx.x; t < 2048; t += 256) hs[t] = h1[(long)b * M_ + t];
    __syncthreads();
    float acc = 0.f;
    for (int k2 = 0; k2 < 2048; k2++) acc += hs[k2] * W2[(long)k2 * M_ + j];
    acc += b2[j];
    h2[(long)b * M_ + j] = fmaxf(acc, 0.f);
}

__global__ __launch_bounds__(256) void mlp3_kernel(const float* __restrict__ h2,
    const float* __restrict__ W3, const float* __restrict__ b3, float* __restrict__ out)
{
    int b = blockIdx.x, tid = threadIdx.x;
    __shared__ float red[256];
    float acc = 0.f;
    for (int k2 = tid; k2 < 2048; k2 += 256) acc += h2[(long)b * M_ + k2] * W3[k2];
    red[tid] = acc; __syncthreads();
    for (int o = 128; o; o >>= 1) { if (tid < o) red[tid] += red[tid + o]; __syncthreads(); }
    if (tid == 0) out[b] = red[0] + b3[0];
}

// ---------------- launch ----------------

extern "C" void kernel_launch(void* const* d_in, const int* in_sizes, int n_in,
                              void* d_out, int out_size, void* d_ws, size_t ws_size,
                              hipStream_t stream)
{
    const float* x    = (const float*)d_in[0];
    const float* Wqkv = (const float*)d_in[1];
    const float* bqkv = (const float*)d_in[2];
    const float* W1   = (const float*)d_in[3];
    const float* b1   = (const float*)d_in[4];
    const float* W2   = (const float*)d_in[5];
    const float* b2   = (const float*)d_in[6];
    const float* W3   = (const float*)d_in[7];
    const float* b3   = (const float*)d_in[8];

    float* out  = (float*)d_out;                    // (B,1) = 16 floats
    float* qout = out + 16;                         // (B,S,D)
    float* kout = qout + (size_t)ROWS * 512;        // (B,S,D)

    char* ws = (char*)d_ws;
    size_t off = 0;
    auto alloc = [&](size_t bytes) -> char* {
        char* p = ws + off; off += (bytes + 255) & ~(size_t)255; return p;
    };
    __hip_bfloat16* Xb = (__hip_bfloat16*)alloc((size_t)ROWS * 512 * 2);
    __hip_bfloat16* Wt = (__hip_bfloat16*)alloc((size_t)N3D * 512 * 2);
    __hip_bfloat16* Vb = (__hip_bfloat16*)alloc((size_t)ROWS * 512 * 2);
    float* sc   = (float*)alloc((size_t)B_ * S_ * 4);
    float* attn = (float*)alloc((size_t)B_ * S_ * 4);
    float* h    = (float*)alloc((size_t)B_ * 512 * 4);
    float* h1   = (float*)alloc((size_t)B_ * M_ * 4);
    float* h2   = (float*)alloc((size_t)B_ * M_ * 4);

    hipLaunchKernelGGL(cvt_x_kernel,   dim3(ROWS * 512 / 8 / 256), dim3(256), 0, stream, x, Xb);
    hipLaunchKernelGGL(cvt_w_kernel,   dim3(N3D * 512 / 256),      dim3(256), 0, stream, Wqkv, Wt);
    hipLaunchKernelGGL(gemm_qkv_kernel, dim3(ROWS / 128, N3D / 128), dim3(256), 0, stream,
                       Xb, Wt, bqkv, qout, kout, Vb);
    hipLaunchKernelGGL(scores_kernel,  dim3(B_, 64), dim3(256), 0, stream, qout, kout, sc);
    hipLaunchKernelGGL(softmax_kernel, dim3(B_),     dim3(256), 0, stream, sc, attn);
    hipLaunchKernelGGL(h_init_kernel,  dim3(B_ * 512 / 256), dim3(256), 0, stream, x, h);
    hipLaunchKernelGGL(sa_kernel,      dim3(B_, 4, 8), dim3(256), 0, stream, Vb, attn, h);
    hipLaunchKernelGGL(mlp1_kernel,    dim3(B_, 8), dim3(256), 0, stream, h, W1, b1, h1);
    hipLaunchKernelGGL(mlp2_kernel,    dim3(B_, 8), dim3(256), 0, stream, h1, W2, b2, h2);
    hipLaunchKernelGGL(mlp3_kernel,    dim3(B_),    dim3(256), 0, stream, h2, W3, b3, out);
}